// Round 6
// baseline (622.679 us; speedup 1.0000x reference)
//
#include <hip/hip_runtime.h>
#include <hip/hip_bf16.h>

// EdgeDetourHead: B=2, N=512, E=128, H=256
// R12: pipeline across j-tiles inside a persistent WG. Evidence: R8/R10/R11
// all pin MfmaUtil*dur at ~44us; occupancy 21->45% made things WORSE. The
// ~28k cyc/round stall is per-tile latency exposure (frag-load latency at
// phase starts, PBT chain, 4 barrier drains), replicated by every wave.
// Fix: WG = 4 waves, TJ=64, loops over 4 j-tiles at fixed (i,b):
//  - w1c frags loop-invariant in regs (loaded once)
//  - D double-buffered; next tile's j-rows loaded at iter start (fly under
//    layer-1 MFMAs), converted+written to spare buffer before the barrier
//  - h1 gets its own LDS region (no overlay) -> L1 and epi1 need no barrier:
//    2 barriers/tile instead of 4
// LDS = 2*17408 + 33792 + 1024 = 69632 B -> 2 WGs/CU. Reg peak ~235 < 256
// (launch_bounds(256,2)) -> no spill (tripwire: WRITE_SIZE).

#define BN 512
#define EE 128
#define HH 256
#define TJ 64            // pair tile (j) per loop iteration

typedef __attribute__((ext_vector_type(8)))  short short8;
typedef __attribute__((ext_vector_type(4)))  short short4v;
typedef __attribute__((ext_vector_type(16))) float f32x16;
typedef __attribute__((ext_vector_type(4)))  float f32x4;

static __device__ __forceinline__ unsigned short f2bf(float f) {
    __bf16 h = (__bf16)f;
    return __builtin_bit_cast(unsigned short, h);
}
static __device__ __forceinline__ f32x16 zero16() {
    f32x16 v;
    #pragma unroll
    for (int i = 0; i < 16; ++i) v[i] = 0.f;
    return v;
}
#define MFMA(a, b, c) __builtin_amdgcn_mfma_f32_32x32x16_bf16((a), (b), (c), 0, 0, 0)

// ---------------- kernel 0: prep ----------------
// blocks 0..255: weight pack. Packed frag idx = ((kb*8 + mtile)*64 + l)*8 + t ;
//   value W[kb*16+(l>>5)*8+t][mtile*32+(l&31)]  == A-frag of W^T.
// blocks 256..511: PA[b,i,f] = h_i@W1a + b1 (fp32, row-major) and
//   PBT[b][f>>2][j][f&3] = (h_j@W1b)[f] (fp32, transposed). 4 nodes per block.
__global__ void prep(const float* __restrict__ node, const float* __restrict__ W1,
                     const float* __restrict__ W2, const float* __restrict__ b1,
                     float* __restrict__ PA, float* __restrict__ PBT,
                     unsigned short* __restrict__ w1c_p, unsigned short* __restrict__ w2_p) {
    int blk = blockIdx.x;
    if (blk < 256) {
        int idx = blk * 256 + threadIdx.x;             // 0..65535
        int t = idx & 7, l = (idx >> 3) & 63, mt = (idx >> 9) & 7, kb = idx >> 12;
        int k = kb * 16 + (l >> 5) * 8 + t, m = mt * 32 + (l & 31);
        w2_p[idx] = f2bf(W2[k * HH + m]);              // W2^T A-frags: kb 0..15
        if (idx < 32768)                               // W1c^T: kb 0..7
            w1c_p[idx] = f2bf(W1[(2 * EE + k) * HH + m]);
    } else {
        int bi0 = (blk - 256) * 4;                     // 4 nodes per block
        int h = threadIdx.x;
        float sa[4], sb[4];
        #pragma unroll
        for (int n = 0; n < 4; ++n) { sa[n] = b1[h]; sb[n] = 0.f; }
        #pragma unroll 8
        for (int e = 0; e < EE; ++e) {
            float wa = W1[e * HH + h];
            float wb = W1[(EE + e) * HH + h];
            #pragma unroll
            for (int n = 0; n < 4; ++n) {
                float nv = node[(size_t)(bi0 + n) * EE + e];   // wave-uniform
                sa[n] += nv * wa;
                sb[n] += nv * wb;
            }
        }
        #pragma unroll
        for (int n = 0; n < 4; ++n) {
            int bi = bi0 + n;
            PA[(size_t)bi * HH + h] = sa[n];
            PBT[(((size_t)(bi >> 9) * 64 + (h >> 2)) * BN + (bi & 511)) * 4 + (h & 3)] = sb[n];
        }
    }
}

// ---------------- kernel 1: fused main, pipelined over 4 j-tiles ----------------
// 4 waves; wave owns m-tiles {2w, 2w+1} (64 feats) x both n-tiles (64 pairs).
__global__ __launch_bounds__(256, 2) void edge_main(
    const float* __restrict__ node, const float* __restrict__ euclid,
    const float* __restrict__ W1, const float* __restrict__ W3,
    const float* __restrict__ b3, const float* __restrict__ b2v,
    const float* __restrict__ PA, const float* __restrict__ PBT,
    const unsigned short* __restrict__ w1c_p, const unsigned short* __restrict__ w2_p,
    float* __restrict__ out)
{
    __shared__ __align__(16) unsigned short ldsD[2][TJ * 136];   // 2 x 17408 B
    __shared__ __align__(16) unsigned short ldsH1[TJ * 264];     // 33792 B
    __shared__ float pp[256];                                    // 1024 B  -> 69632 B

    const int jg = blockIdx.x, i = blockIdx.y, b = blockIdx.z;
    const int tid = threadIdx.x, wave = tid >> 6, lane = tid & 63;
    const int m0 = lane & 31, q = lane >> 5;
    const int row = tid >> 2, q4 = tid & 3;            // D-build: 4 threads/j-row

    // ---- loop-invariant state ----
    // i-row slice for D build (8 f32x4 = 32 VGPR)
    const f32x4* hv = (const f32x4*)(node + ((size_t)b * BN + i) * EE);
    f32x4 hi[8];
    #pragma unroll
    for (int c = 0; c < 8; ++c) hi[c] = hv[q4 * 8 + c];

    // W1c^T A-frags, resident (16 x short8 = 64 VGPR)
    short8 wcf[2][8];
    {
        const short8* wcp = (const short8*)w1c_p;
        #pragma unroll
        for (int kb = 0; kb < 8; ++kb) {
            wcf[0][kb] = wcp[(kb * 8 + wave * 2 + 0) * 64 + lane];
            wcf[1][kb] = wcp[(kb * 8 + wave * 2 + 1) * 64 + lane];
        }
    }

    const float* erow = euclid + ((size_t)b * BN + i) * BN;
    const float* paB  = PA + ((size_t)b * BN + i) * HH;
    const float* wd   = W1 + (size_t)(3 * EE) * HH;    // w1d row (384)
    const float* pbt  = PBT + (size_t)b * 64 * BN * 4;
    const short8* w2f = (const short8*)w2_p;

    // ---- prologue: load j-rows(0), build D[0] ----
    int jbase = jg * 4 * TJ;
    {
        const f32x4* nj = (const f32x4*)(node + ((size_t)b * BN + jbase + row) * EE);
        f32x4 jr[8];
        #pragma unroll
        for (int c = 0; c < 8; ++c) jr[c] = nj[q4 * 8 + c];
        #pragma unroll
        for (int g = 0; g < 4; ++g) {
            short8 pd;
            #pragma unroll
            for (int u = 0; u < 4; ++u) {
                pd[u]     = (short)f2bf(fabsf(jr[g * 2][u]     - hi[g * 2][u]));
                pd[4 + u] = (short)f2bf(fabsf(jr[g * 2 + 1][u] - hi[g * 2 + 1][u]));
            }
            *(short8*)&ldsD[0][row * 136 + q4 * 32 + g * 8] = pd;
        }
    }
    __syncthreads();

    int cur = 0;
    for (int t = 0; t < 4; ++t, jbase += TJ) {
        // ---- issue next tile's j-row loads (fly under layer 1) ----
        f32x4 jn[8];
        if (t < 3) {
            const f32x4* nj = (const f32x4*)(node + ((size_t)b * BN + jbase + TJ + row) * EE);
            #pragma unroll
            for (int c = 0; c < 8; ++c) jn[c] = nj[q4 * 8 + c];
        }
        float ev[2];
        #pragma unroll
        for (int nt = 0; nt < 2; ++nt) ev[nt] = erow[jbase + nt * 32 + m0];

        // ---- layer 1: C1^T = W1c^T @ D^T, K=128 (frags resident) ----
        f32x16 acc[2][2];
        #pragma unroll
        for (int mt = 0; mt < 2; ++mt)
            #pragma unroll
            for (int nt = 0; nt < 2; ++nt) acc[mt][nt] = zero16();
        #pragma unroll
        for (int kb = 0; kb < 8; ++kb) {
            #pragma unroll
            for (int nt = 0; nt < 2; ++nt) {
                short8 bD = *(const short8*)&ldsD[cur][(nt * 32 + m0) * 136 + kb * 16 + q * 8];
                acc[0][nt] = MFMA(wcf[0][kb], bD, acc[0][nt]);
                acc[1][nt] = MFMA(wcf[1][kb], bD, acc[1][nt]);
            }
        }

        // ---- epi1 (no barrier needed vs layer 1: disjoint LDS regions) ----
        #pragma unroll
        for (int mt = 0; mt < 2; ++mt) {
            #pragma unroll
            for (int rg = 0; rg < 4; ++rg) {
                int f0 = (wave * 2 + mt) * 32 + rg * 8;          // wave-uniform
                f32x4 plo = *(const f32x4*)&paB[f0];
                f32x4 phi = *(const f32x4*)&paB[f0 + 4];
                f32x4 dlo = *(const f32x4*)&wd[f0];
                f32x4 dhi = *(const f32x4*)&wd[f0 + 4];
                #pragma unroll
                for (int nt = 0; nt < 2; ++nt) {
                    f32x4 pbv = *(const f32x4*)&pbt[
                        (((size_t)(f0 >> 2) + q) * BN + jbase + nt * 32 + m0) * 4];
                    short4v w;
                    #pragma unroll
                    for (int u = 0; u < 4; ++u) {
                        float pav = q ? phi[u] : plo[u];
                        float wdv = q ? dhi[u] : dlo[u];
                        float v = acc[mt][nt][rg * 4 + u] + pav + pbv[u] + ev[nt] * wdv;
                        v = v > 0.f ? v : 0.f;
                        w[u] = (short)f2bf(v);
                    }
                    *(short4v*)&ldsH1[(nt * 32 + m0) * 264 + f0 + 4 * q] = w;
                }
            }
        }

        // ---- build D(t+1) into spare buffer (j-rows already in flight) ----
        if (t < 3) {
            #pragma unroll
            for (int g = 0; g < 4; ++g) {
                short8 pd;
                #pragma unroll
                for (int u = 0; u < 4; ++u) {
                    pd[u]     = (short)f2bf(fabsf(jn[g * 2][u]     - hi[g * 2][u]));
                    pd[4 + u] = (short)f2bf(fabsf(jn[g * 2 + 1][u] - hi[g * 2 + 1][u]));
                }
                *(short8*)&ldsD[cur ^ 1][row * 136 + q4 * 32 + g * 8] = pd;
            }
        }
        __syncthreads();                               // B1: h1 + D[next] ready

        // ---- layer 2: C2^T = W2^T @ h1^T, K=256 (w2 frags streamed) ----
        f32x16 c2[2][2];
        #pragma unroll
        for (int mt = 0; mt < 2; ++mt)
            #pragma unroll
            for (int nt = 0; nt < 2; ++nt) c2[mt][nt] = zero16();
        #pragma unroll
        for (int kb = 0; kb < 16; ++kb) {
            short8 a0 = w2f[(kb * 8 + wave * 2 + 0) * 64 + lane];
            short8 a1 = w2f[(kb * 8 + wave * 2 + 1) * 64 + lane];
            #pragma unroll
            for (int nt = 0; nt < 2; ++nt) {
                short8 bh = *(const short8*)&ldsH1[(nt * 32 + m0) * 264 + kb * 16 + q * 8];
                c2[0][nt] = MFMA(a0, bh, c2[0][nt]);
                c2[1][nt] = MFMA(a1, bh, c2[1][nt]);
            }
        }

        // ---- layer 3 in registers ----
        {
            float s[2] = {0.f, 0.f};
            #pragma unroll
            for (int mt = 0; mt < 2; ++mt) {
                #pragma unroll
                for (int rg = 0; rg < 4; ++rg) {
                    int f0 = (wave * 2 + mt) * 32 + rg * 8;      // wave-uniform
                    f32x4 blo = *(const f32x4*)&b2v[f0];
                    f32x4 bhi = *(const f32x4*)&b2v[f0 + 4];
                    f32x4 wlo = *(const f32x4*)&W3[f0];
                    f32x4 whi = *(const f32x4*)&W3[f0 + 4];
                    #pragma unroll
                    for (int u = 0; u < 4; ++u) {
                        float bb = q ? bhi[u] : blo[u];
                        float ww = q ? whi[u] : wlo[u];
                        #pragma unroll
                        for (int nt = 0; nt < 2; ++nt) {
                            float h2 = c2[mt][nt][rg * 4 + u] + bb;
                            h2 = h2 > 0.f ? h2 : 0.f;
                            s[nt] += h2 * ww;
                        }
                    }
                }
            }
            #pragma unroll
            for (int nt = 0; nt < 2; ++nt)
                s[nt] += __shfl_xor(s[nt], 32, 64);   // fold q-halves
            if (lane < 32) {
                #pragma unroll
                for (int nt = 0; nt < 2; ++nt)
                    pp[(wave * 2 + nt) * 32 + lane] = s[nt];
            }
        }
        __syncthreads();                               // B2: pp ready, h1 free
        if (tid < TJ) {
            int nt = tid >> 5, l5 = tid & 31;
            float v = b3[0];
            #pragma unroll
            for (int wm = 0; wm < 4; ++wm)
                v += pp[(wm * 2 + nt) * 32 + l5];
            out[((size_t)b * BN + i) * BN + jbase + tid] = v;
        }
        cur ^= 1;
    }
}

// ---------------- kernel 2: in-place symmetrize + zero diagonal ----------------
__global__ void symmetrize(float* __restrict__ out) {
    int b = blockIdx.z, ti = blockIdx.y, tj = blockIdx.x;
    if (tj < ti) return;
    int i = ti * 32 + threadIdx.y, j = tj * 32 + threadIdx.x;
    float* p = out + (size_t)b * BN * BN;
    if (i == j) { p[(size_t)i * BN + j] = 0.f; return; }
    if (j < i) return;
    float a = p[(size_t)i * BN + j];
    float c = p[(size_t)j * BN + i];
    float v = 0.5f * (a + c);
    p[(size_t)i * BN + j] = v;
    p[(size_t)j * BN + i] = v;
}

extern "C" void kernel_launch(void* const* d_in, const int* in_sizes, int n_in,
                              void* d_out, int out_size, void* d_ws, size_t ws_size,
                              hipStream_t stream) {
    const float* node   = (const float*)d_in[0];
    const float* euclid = (const float*)d_in[2];
    const float* W1     = (const float*)d_in[3];
    const float* b1     = (const float*)d_in[4];
    const float* W2     = (const float*)d_in[5];
    const float* b2     = (const float*)d_in[6];
    const float* W3     = (const float*)d_in[7];
    const float* b3     = (const float*)d_in[8];
    float* out = (float*)d_out;

    char* ws = (char*)d_ws;
    float*          PA    = (float*)ws;                                   // 1 MB
    float*          PBT   = (float*)(ws + (1u << 20));                    // 1 MB
    unsigned short* w1c_p = (unsigned short*)(ws + (2u << 20));           // 64 KB
    unsigned short* w2_p  = (unsigned short*)(ws + (2u << 20) + 65536);   // 128 KB

    prep<<<512, 256, 0, stream>>>(node, W1, W2, b1, PA, PBT, w1c_p, w2_p);
    edge_main<<<dim3(2, BN, 2), 256, 0, stream>>>(
        node, euclid, W1, W3, b3, b2, PA, PBT, w1c_p, w2_p, out);
    symmetrize<<<dim3(BN / 32, BN / 32, 2), dim3(32, 32), 0, stream>>>(out);
}

// Round 7
// 338.814 us; speedup vs baseline: 1.8378x; 1.8378x over previous
//
#include <hip/hip_runtime.h>
#include <hip/hip_bf16.h>

// EdgeDetourHead: B=2, N=512, E=128, H=256
// R13: 8-wave / 1-WG-per-CU persistent structure.
// Evidence: R8/R10/R11 pin MfmaUtil*dur ~44us; occupancy up = worse; R9/R12
// died of register spill. Diagnosis: ~100 VMEM ops/wave/tile (weight frags,
// PBT, node) with shallow in-flight depth + 4 barrier drains = ~4.5x latency
// inflation over the 12k-cycle bottom-up critical path.
// Design:
//  - 512 thr = 8 waves; wave OWNS one 32-feat m-tile: acc[4]/c2[4] = 64 AGPR
//    (shared liveness), wcf = 8 frags = 32 VGPR, jr = 32 VGPR. Fits 256 cap.
//  - 1 WG/CU -> 160KB LDS: D dbuf (2x34.8K) + h1 separate (67.6K) + w2 dbuf
//    (16K) + pp (4K) = 157.7KB. No D/h1 overlay -> 2 raw barriers/iter
//    (lgkmcnt(0)-only: LDS is the only cross-wave channel; vmcnt survives).
//  - persistent over NI=4 i at fixed (jt,b): wcf/jr loaded once; D(i+1) built
//    from registers under L1(i) MFMAs.
//  - w2 via global_load_lds: wave stages its OWN 1KB kb-chunk (lane-linear
//    packed layout == DMA base+lane*16) -> per-wave vmcnt(1) counting, no
//    cross-wave sync; lgkmcnt(0) before each re-stage prevents overwrite race.

#define BN 512
#define EE 128
#define HH 256
#define NI 4             // i-rows per persistent WG

typedef __attribute__((ext_vector_type(8)))  short short8;
typedef __attribute__((ext_vector_type(4)))  short short4v;
typedef __attribute__((ext_vector_type(16))) float f32x16;
typedef __attribute__((ext_vector_type(4)))  float f32x4;

static __device__ __forceinline__ unsigned short f2bf(float f) {
    __bf16 h = (__bf16)f;
    return __builtin_bit_cast(unsigned short, h);
}
static __device__ __forceinline__ f32x16 zero16() {
    f32x16 v;
    #pragma unroll
    for (int i = 0; i < 16; ++i) v[i] = 0.f;
    return v;
}
static __device__ __forceinline__ void stage16(const unsigned short* g, unsigned short* l) {
    __builtin_amdgcn_global_load_lds(
        (const __attribute__((address_space(1))) unsigned int*)g,
        (__attribute__((address_space(3))) unsigned int*)l, 16, 0, 0);
}
#define MFMA(a, b, c) __builtin_amdgcn_mfma_f32_32x32x16_bf16((a), (b), (c), 0, 0, 0)
#define LGKM0() asm volatile("s_waitcnt lgkmcnt(0)" ::: "memory")

// ---------------- kernel 0: prep (unchanged from R11) ----------------
__global__ void prep(const float* __restrict__ node, const float* __restrict__ W1,
                     const float* __restrict__ W2, const float* __restrict__ b1,
                     float* __restrict__ PA, float* __restrict__ PBT,
                     unsigned short* __restrict__ w1c_p, unsigned short* __restrict__ w2_p) {
    int blk = blockIdx.x;
    if (blk < 256) {
        int idx = blk * 256 + threadIdx.x;             // 0..65535
        int t = idx & 7, l = (idx >> 3) & 63, mt = (idx >> 9) & 7, kb = idx >> 12;
        int k = kb * 16 + (l >> 5) * 8 + t, m = mt * 32 + (l & 31);
        w2_p[idx] = f2bf(W2[k * HH + m]);              // W2^T A-frags: kb 0..15
        if (idx < 32768)                               // W1c^T: kb 0..7
            w1c_p[idx] = f2bf(W1[(2 * EE + k) * HH + m]);
    } else {
        int bi0 = (blk - 256) * 4;                     // 4 nodes per block
        int h = threadIdx.x;
        float sa[4], sb[4];
        #pragma unroll
        for (int n = 0; n < 4; ++n) { sa[n] = b1[h]; sb[n] = 0.f; }
        #pragma unroll 8
        for (int e = 0; e < EE; ++e) {
            float wa = W1[e * HH + h];
            float wb = W1[(EE + e) * HH + h];
            #pragma unroll
            for (int n = 0; n < 4; ++n) {
                float nv = node[(size_t)(bi0 + n) * EE + e];   // wave-uniform
                sa[n] += nv * wa;
                sb[n] += nv * wb;
            }
        }
        #pragma unroll
        for (int n = 0; n < 4; ++n) {
            int bi = bi0 + n;
            PA[(size_t)bi * HH + h] = sa[n];
            PBT[(((size_t)(bi >> 9) * 64 + (h >> 2)) * BN + (bi & 511)) * 4 + (h & 3)] = sb[n];
        }
    }
}

// ---------------- kernel 1: fused main, persistent over NI i-rows ----------------
__global__ __launch_bounds__(512, 2) void edge_main(
    const float* __restrict__ node, const float* __restrict__ euclid,
    const float* __restrict__ W1, const float* __restrict__ W3,
    const float* __restrict__ b3, const float* __restrict__ b2v,
    const float* __restrict__ PA, const float* __restrict__ PBT,
    const unsigned short* __restrict__ w1c_p, const unsigned short* __restrict__ w2_p,
    float* __restrict__ out)
{
    __shared__ __align__(16) unsigned short ldsD[2][128 * 136];  // 2 x 34816 B
    __shared__ __align__(16) unsigned short ldsH1[128 * 264];    // 67584 B
    __shared__ __align__(16) unsigned short ldsW2[2][8 * 64 * 8];// 2 x 8192 B
    __shared__ float pp[1024];                                   // 4096 B -> 157696 B

    const int jt = blockIdx.x, ig = blockIdx.y, b = blockIdx.z;
    const int jbase = jt * 128, i0 = ig * NI;
    const int tid = threadIdx.x, wave = tid >> 6, lane = tid & 63;
    const int m0 = lane & 31, q = lane >> 5;
    const int row = tid >> 2, q4 = tid & 3;            // D-build: 4 threads/j-row

    // ---- loop-invariant register state ----
    short8 wcf[8];                                     // this wave's W1c^T frags (32 VGPR)
    {
        const short8* wcp = (const short8*)w1c_p;
        #pragma unroll
        for (int kb = 0; kb < 8; ++kb)
            wcf[kb] = wcp[(kb * 8 + wave) * 64 + lane];
    }
    f32x4 jr[8];                                       // this thread's j-row slice (32 VGPR)
    {
        const f32x4* nj = (const f32x4*)(node + ((size_t)b * BN + jbase + row) * EE);
        #pragma unroll
        for (int c = 0; c < 8; ++c) jr[c] = nj[q4 * 8 + c];
    }
    const float* pbt = PBT + (size_t)b * 64 * BN * 4;
    const float* wd  = W1 + (size_t)(3 * EE) * HH;     // w1d row (384)

    // ---- prologue: build D[0] for i = i0 ----
    {
        const f32x4* hv = (const f32x4*)(node + ((size_t)b * BN + i0) * EE);
        f32x4 hn[8];
        #pragma unroll
        for (int c = 0; c < 8; ++c) hn[c] = hv[q4 * 8 + c];
        #pragma unroll
        for (int g = 0; g < 4; ++g) {
            short8 pd;
            #pragma unroll
            for (int u = 0; u < 4; ++u) {
                pd[u]     = (short)f2bf(fabsf(jr[g * 2][u]     - hn[g * 2][u]));
                pd[4 + u] = (short)f2bf(fabsf(jr[g * 2 + 1][u] - hn[g * 2 + 1][u]));
            }
            *(short8*)&ldsD[0][row * 136 + q4 * 32 + g * 8] = pd;
        }
    }
    LGKM0();
    __builtin_amdgcn_s_barrier();

    int cur = 0;
    for (int it = 0; it < NI; ++it) {
        const int i = i0 + it;

        // ---- issue next i-row loads (consumed in D-build below) ----
        f32x4 hn[8];
        if (it < NI - 1) {
            const f32x4* hv = (const f32x4*)(node + ((size_t)b * BN + i + 1) * EE);
            #pragma unroll
            for (int c = 0; c < 8; ++c) hn[c] = hv[q4 * 8 + c];
        }

        // ---- layer 1: C1^T = W1c^T @ D^T, K=128 (A-frags in registers) ----
        f32x16 acc[4];
        #pragma unroll
        for (int nt = 0; nt < 4; ++nt) acc[nt] = zero16();
        #pragma unroll
        for (int kb = 0; kb < 8; ++kb) {
            #pragma unroll
            for (int nt = 0; nt < 4; ++nt) {
                short8 bD = *(const short8*)&ldsD[cur][(nt * 32 + m0) * 136 + kb * 16 + q * 8];
                acc[nt] = MFMA(wcf[kb], bD, acc[nt]);
            }
        }

        // ---- build D(it+1) into spare buffer (overlaps L1's MFMA pipe) ----
        if (it < NI - 1) {
            #pragma unroll
            for (int g = 0; g < 4; ++g) {
                short8 pd;
                #pragma unroll
                for (int u = 0; u < 4; ++u) {
                    pd[u]     = (short)f2bf(fabsf(jr[g * 2][u]     - hn[g * 2][u]));
                    pd[4 + u] = (short)f2bf(fabsf(jr[g * 2 + 1][u] - hn[g * 2 + 1][u]));
                }
                *(short8*)&ldsD[cur ^ 1][row * 136 + q4 * 32 + g * 8] = pd;
            }
        }

        // ---- epi1: h1[pair][f] = relu(C1^T + PA[i][f] + PB[j][f] + e*w1d[f]) ----
        {
            const float* paB  = PA + ((size_t)b * BN + i) * HH;
            const float* erow = euclid + ((size_t)b * BN + i) * BN + jbase;
            float ev[4];
            #pragma unroll
            for (int nt = 0; nt < 4; ++nt) ev[nt] = erow[nt * 32 + m0];
            #pragma unroll
            for (int rg = 0; rg < 4; ++rg) {
                int f0 = wave * 32 + rg * 8;                     // wave-uniform
                f32x4 plo = *(const f32x4*)&paB[f0];
                f32x4 phi = *(const f32x4*)&paB[f0 + 4];
                f32x4 dlo = *(const f32x4*)&wd[f0];
                f32x4 dhi = *(const f32x4*)&wd[f0 + 4];
                #pragma unroll
                for (int nt = 0; nt < 4; ++nt) {
                    f32x4 pbv = *(const f32x4*)&pbt[
                        (((size_t)(f0 >> 2) + q) * BN + jbase + nt * 32 + m0) * 4];
                    short4v w;
                    #pragma unroll
                    for (int u = 0; u < 4; ++u) {
                        float pav = q ? phi[u] : plo[u];
                        float wdv = q ? dhi[u] : dlo[u];
                        float v = acc[nt][rg * 4 + u] + pav + pbv[u] + ev[nt] * wdv;
                        v = v > 0.f ? v : 0.f;
                        w[u] = (short)f2bf(v);
                    }
                    *(short4v*)&ldsH1[(nt * 32 + m0) * 264 + f0 + 4 * q] = w;
                }
            }
        }

        // ---- stage first two w2 kb-chunks (async, survive the raw barrier) ----
        stage16(w2_p + (size_t)((0 * 8 + wave) * 512) + lane * 8, &ldsW2[0][wave * 512]);
        stage16(w2_p + (size_t)((1 * 8 + wave) * 512) + lane * 8, &ldsW2[1][wave * 512]);
        LGKM0();
        __builtin_amdgcn_s_barrier();                  // B2: h1 + D[next] visible

        // ---- layer 2: C2^T = W2^T @ h1^T, K=256, w2 double-buffered via DMA ----
        f32x16 c2[4];
        #pragma unroll
        for (int nt = 0; nt < 4; ++nt) c2[nt] = zero16();
        #pragma unroll
        for (int kb = 0; kb < 16; ++kb) {
            if (kb < 15) { asm volatile("s_waitcnt vmcnt(1)" ::: "memory"); }
            else         { asm volatile("s_waitcnt vmcnt(0)" ::: "memory"); }
            short8 a = *(const short8*)&ldsW2[kb & 1][wave * 512 + lane * 8];
            #pragma unroll
            for (int nt = 0; nt < 4; ++nt) {
                short8 bh = *(const short8*)&ldsH1[(nt * 32 + m0) * 264 + kb * 16 + q * 8];
                c2[nt] = MFMA(a, bh, c2[nt]);
            }
            LGKM0();                                   // reads retired before overwrite
            if (kb < 14)
                stage16(w2_p + (size_t)(((kb + 2) * 8 + wave) * 512) + lane * 8,
                        &ldsW2[kb & 1][wave * 512]);
        }

        // ---- layer 3 in registers ----
        {
            float s[4] = {0.f, 0.f, 0.f, 0.f};
            #pragma unroll
            for (int rg = 0; rg < 4; ++rg) {
                int f0 = wave * 32 + rg * 8;                     // wave-uniform
                f32x4 blo = *(const f32x4*)&b2v[f0];
                f32x4 bhi = *(const f32x4*)&b2v[f0 + 4];
                f32x4 wlo = *(const f32x4*)&W3[f0];
                f32x4 whi = *(const f32x4*)&W3[f0 + 4];
                #pragma unroll
                for (int u = 0; u < 4; ++u) {
                    float bb = q ? bhi[u] : blo[u];
                    float ww = q ? whi[u] : wlo[u];
                    #pragma unroll
                    for (int nt = 0; nt < 4; ++nt) {
                        float h2 = c2[nt][rg * 4 + u] + bb;
                        h2 = h2 > 0.f ? h2 : 0.f;
                        s[nt] += h2 * ww;
                    }
                }
            }
            #pragma unroll
            for (int nt = 0; nt < 4; ++nt)
                s[nt] += __shfl_xor(s[nt], 32, 64);   // fold q-halves
            if (lane < 32) {
                #pragma unroll
                for (int nt = 0; nt < 4; ++nt)
                    pp[wave * 128 + nt * 32 + lane] = s[nt];
            }
        }
        LGKM0();
        __builtin_amdgcn_s_barrier();                  // B1: pp visible, h1/D free
        if (tid < 128) {
            float v = b3[0];
            #pragma unroll
            for (int w8 = 0; w8 < 8; ++w8) v += pp[w8 * 128 + tid];
            out[((size_t)b * BN + i) * BN + jbase + tid] = v;
        }
        cur ^= 1;
    }
}

// ---------------- kernel 2: in-place symmetrize + zero diagonal ----------------
__global__ void symmetrize(float* __restrict__ out) {
    int b = blockIdx.z, ti = blockIdx.y, tj = blockIdx.x;
    if (tj < ti) return;
    int i = ti * 32 + threadIdx.y, j = tj * 32 + threadIdx.x;
    float* p = out + (size_t)b * BN * BN;
    if (i == j) { p[(size_t)i * BN + j] = 0.f; return; }
    if (j < i) return;
    float a = p[(size_t)i * BN + j];
    float c = p[(size_t)j * BN + i];
    float v = 0.5f * (a + c);
    p[(size_t)i * BN + j] = v;
    p[(size_t)j * BN + i] = v;
}

extern "C" void kernel_launch(void* const* d_in, const int* in_sizes, int n_in,
                              void* d_out, int out_size, void* d_ws, size_t ws_size,
                              hipStream_t stream) {
    const float* node   = (const float*)d_in[0];
    const float* euclid = (const float*)d_in[2];
    const float* W1     = (const float*)d_in[3];
    const float* b1     = (const float*)d_in[4];
    const float* W2     = (const float*)d_in[5];
    const float* b2     = (const float*)d_in[6];
    const float* W3     = (const float*)d_in[7];
    const float* b3     = (const float*)d_in[8];
    float* out = (float*)d_out;

    char* ws = (char*)d_ws;
    float*          PA    = (float*)ws;                                   // 1 MB
    float*          PBT   = (float*)(ws + (1u << 20));                    // 1 MB
    unsigned short* w1c_p = (unsigned short*)(ws + (2u << 20));           // 64 KB
    unsigned short* w2_p  = (unsigned short*)(ws + (2u << 20) + 65536);   // 128 KB

    prep<<<512, 256, 0, stream>>>(node, W1, W2, b1, PA, PBT, w1c_p, w2_p);
    edge_main<<<dim3(4, BN / NI, 2), 512, 0, stream>>>(
        node, euclid, W1, W3, b3, b2, PA, PBT, w1c_p, w2_p, out);
    symmetrize<<<dim3(BN / 32, BN / 32, 2), dim3(32, 32), 0, stream>>>(out);
}